// Round 2
// baseline (18733.485 us; speedup 1.0000x reference)
//
#include <hip/hip_runtime.h>
#include <hip/hip_fp16.h>

typedef _Float16 half_t;
typedef _Float16 half2_t __attribute__((ext_vector_type(2)));
typedef unsigned int u32;

#define SEQ   512
#define HID   512
#define NSK   1024
#define INDIM 2048
#define G4    2048
#define HHALF 32768      // half elements per timestep (64 KB)
#define ROWW  260        // padded LDS row stride (u32 words): banks spread by 4/lane
#define ROWQ  65         // padded LDS row stride (uint4)

// ---- workspace layout (bytes) ----
#define H1_OFF    0ull
#define H2_OFF    33554432ull
#define B0_OFF    67108864ull
#define B1_OFF    67117056ull
#define WHH0_OFF  67125248ull
#define WIH1_OFF  69222400ull
#define WHH1_OFF  71319552ull
#define FCW_OFF   73416704ull
#define FLG_OFF   74465280ull   // arrive[512] + go -> 513 u32

__device__ __forceinline__ float sigmoidf_(float x) {
    return 1.0f / (1.0f + __expf(-x));
}
__device__ __forceinline__ float tanhf_(float x) {
    return 2.0f * sigmoidf_(2.0f * x) - 1.0f;
}

__device__ __forceinline__ float dot2_(u32 a, u32 b, float c) {
    half2_t ha = __builtin_bit_cast(half2_t, a);
    half2_t hb = __builtin_bit_cast(half2_t, b);
#if __has_builtin(__builtin_amdgcn_fdot2)
    return __builtin_amdgcn_fdot2(ha, hb, c, false);
#else
    return c + (float)ha[0] * (float)hb[0] + (float)ha[1] * (float)hb[1];
#endif
}

// stage one timestep's h (64 KB, global layout [b][k2]) into padded LDS rows
__device__ __forceinline__ void stage_pad(u32* sh, const half_t* src, int tid) {
    const uint4* s = (const uint4*)src;
#pragma unroll
    for (int i = 0; i < 16; ++i) {
        int f = tid + i * 256;          // source quad 0..4095
        int b = f >> 6, q = f & 63;
        *(uint4*)(sh + b * ROWW + q * 4) = s[f];
    }
}

// ---- prep: f16 weight copies + fused biases + barrier-flag zeroing ----
__global__ __launch_bounds__(256) void prep_kernel(
    const float* __restrict__ Whh0, const float* __restrict__ Wih1,
    const float* __restrict__ Whh1, const float* __restrict__ fcW,
    const float* __restrict__ bih0, const float* __restrict__ bhh0,
    const float* __restrict__ bih1, const float* __restrict__ bhh1,
    half_t* __restrict__ whh0h, half_t* __restrict__ wih1h,
    half_t* __restrict__ whh1h, half_t* __restrict__ fcwh,
    float* __restrict__ b0, float* __restrict__ b1, u32* __restrict__ flags)
{
    int i = blockIdx.x * 256 + threadIdx.x;
    if (i < G4 * HID) {
        whh0h[i] = (half_t)Whh0[i];
        wih1h[i] = (half_t)Wih1[i];
        whh1h[i] = (half_t)Whh1[i];
    }
    if (i < NSK * HID) fcwh[i] = (half_t)fcW[i];
    if (i < G4) { b0[i] = bih0[i] + bhh0[i]; b1[i] = bih1[i] + bhh1[i]; }
    if (i < 513) flags[i] = 0;
}

struct PArgs {
    const int* skills; const int* corrects;
    const float* Wih0;
    const half_t* Whh0; const half_t* Wih1; const half_t* Whh1;
    const float* b0; const float* b1;
    half_t* h1; half_t* h2;
    u32* arrive; u32* go;
};

__device__ __forceinline__ void gridbar(u32* arrive, u32* go, int wg, u32 tick, int tid) {
    __syncthreads();    // all WG work (incl. global h stores) drained before arrive
    if (tid == 0)
        __hip_atomic_store(&arrive[wg], tick, __ATOMIC_RELEASE, __HIP_MEMORY_SCOPE_AGENT);
    if (wg == 0) {
        for (int i = tid; i < 512; i += 256) {
            int guard = 0;
            while (__hip_atomic_load(&arrive[i], __ATOMIC_RELAXED, __HIP_MEMORY_SCOPE_AGENT) < tick) {
                __builtin_amdgcn_s_sleep(1);
                if (++guard > (1 << 22)) break;   // deadlock escape -> visible failure
            }
        }
        __threadfence();
        __syncthreads();
        if (tid == 0)
            __hip_atomic_store(go, tick, __ATOMIC_RELEASE, __HIP_MEMORY_SCOPE_AGENT);
    } else {
        if (tid == 0) {
            int guard = 0;
            while (__hip_atomic_load(go, __ATOMIC_RELAXED, __HIP_MEMORY_SCOPE_AGENT) < tick) {
                __builtin_amdgcn_s_sleep(1);
                if (++guard > (1 << 22)) break;
            }
            __threadfence();
        }
        __syncthreads();
    }
}

// ---- persistent 2-layer LSTM: 512 WGs, 513 ticks, flag barrier per tick ----
__global__ __launch_bounds__(256, 2) void lstm_persist(PArgs a) {
    __shared__ u32 sh[64 * ROWW];    // 66560 B padded h tile
    __shared__ float csh[128];       // c-state for this WG's 2 units x 64 batch
    __shared__ float gl[512];        // gate exchange

    const int wg = blockIdx.x;
    const bool is_l1 = wg >= 256;
    const int g = wg & 255;
    const int tid = threadIdx.x;
    const int lane = tid & 63;       // batch
    const int w = tid >> 6;          // gate 0..3
    const int r0 = __builtin_amdgcn_readfirstlane(w * HID + g * 2);
    const int r1 = r0 + 1;

    const half_t* Whh = is_l1 ? a.Whh1 : a.Whh0;
    const float* bias = is_l1 ? a.b1 : a.b0;
    half_t* hout_base = is_l1 ? a.h2 : a.h1;
    const half_t* hprev_base = is_l1 ? a.h2 : a.h1;

    const uint4* wa4 = (const uint4*)(Whh + (size_t)r0 * HID);
    const uint4* wb4 = (const uint4*)(Whh + (size_t)r1 * HID);
    const uint4* xa4 = (const uint4*)(a.Wih1 + (size_t)r0 * HID);
    const uint4* xb4 = (const uint4*)(a.Wih1 + (size_t)r1 * HID);

    for (int tau = 0; tau <= SEQ; ++tau) {
        const int t = is_l1 ? tau - 1 : tau;
        const bool active = is_l1 ? (tau >= 1) : (tau < SEQ);
        if (active) {
            float acc0 = bias[r0], acc1 = bias[r1];

            if (!is_l1) {
                int sk = a.skills[lane * SEQ + t];
                int co = a.corrects[lane * SEQ + t];
                if (sk >= 0) {
                    int idx = sk + NSK * ((co == 1) ? 0 : 1);
                    acc0 += a.Wih0[(size_t)r0 * INDIM + idx];
                    acc1 += a.Wih0[(size_t)r1 * INDIM + idx];
                }
            } else {
                stage_pad(sh, a.h1 + (size_t)t * HHALF, tid);
                __syncthreads();
                const uint4* hq = ((const uint4*)sh) + lane * ROWQ;
#pragma unroll 4
                for (int q = 0; q < 64; ++q) {
                    uint4 hp = hq[q]; uint4 va = xa4[q]; uint4 vb = xb4[q];
                    acc0 = dot2_(hp.x, va.x, acc0); acc0 = dot2_(hp.y, va.y, acc0);
                    acc0 = dot2_(hp.z, va.z, acc0); acc0 = dot2_(hp.w, va.w, acc0);
                    acc1 = dot2_(hp.x, vb.x, acc1); acc1 = dot2_(hp.y, vb.y, acc1);
                    acc1 = dot2_(hp.z, vb.z, acc1); acc1 = dot2_(hp.w, vb.w, acc1);
                }
                __syncthreads();
            }

            if (t > 0) {
                stage_pad(sh, hprev_base + (size_t)(t - 1) * HHALF, tid);
                __syncthreads();
                const uint4* hq = ((const uint4*)sh) + lane * ROWQ;
#pragma unroll 4
                for (int q = 0; q < 64; ++q) {
                    uint4 hp = hq[q]; uint4 va = wa4[q]; uint4 vb = wb4[q];
                    acc0 = dot2_(hp.x, va.x, acc0); acc0 = dot2_(hp.y, va.y, acc0);
                    acc0 = dot2_(hp.z, va.z, acc0); acc0 = dot2_(hp.w, va.w, acc0);
                    acc1 = dot2_(hp.x, vb.x, acc1); acc1 = dot2_(hp.y, vb.y, acc1);
                    acc1 = dot2_(hp.z, vb.z, acc1); acc1 = dot2_(hp.w, vb.w, acc1);
                }
                __syncthreads();
            }

            gl[w * 128 + lane] = acc0;
            gl[w * 128 + 64 + lane] = acc1;
            __syncthreads();

            if (w < 2) {
                int u = g * 2 + w;
                float gi = gl[0 * 128 + w * 64 + lane];
                float gf = gl[1 * 128 + w * 64 + lane];
                float gg = gl[2 * 128 + w * 64 + lane];
                float go_ = gl[3 * 128 + w * 64 + lane];
                float cold = (t > 0) ? csh[w * 64 + lane] : 0.0f;
                float cnew = sigmoidf_(gf) * cold + sigmoidf_(gi) * tanhf_(gg);
                float hnew = sigmoidf_(go_) * tanhf_(cnew);
                csh[w * 64 + lane] = cnew;
                hout_base[(size_t)t * HHALF + lane * 512 + u] = (half_t)hnew;
            }
        }
        gridbar(a.arrive, a.go, wg, (u32)(tau + 1), tid);
    }
}

// ---- projection: out[b][t][n] = sigmoid(h2[t][b][:] . fcW[n] + fcb[n]) ----
__global__ __launch_bounds__(256) void proj_kernel(
    const half_t* __restrict__ h2, const half_t* __restrict__ fcwh,
    const float* __restrict__ fcb, float* __restrict__ out)
{
    __shared__ u32 sh[64 * ROWW];    // padded h tile; reused as 64x65 f32 out-stage

    const int t = blockIdx.x >> 4;
    const int nt = blockIdx.x & 15;
    const int tid = threadIdx.x;
    const int lane = tid & 63;       // batch
    const int w = tid >> 6;

    stage_pad(sh, h2 + (size_t)t * HHALF, tid);
    __syncthreads();

    const int n0 = __builtin_amdgcn_readfirstlane(nt * 64 + w * 16);
    float acc[16];
#pragma unroll
    for (int j = 0; j < 16; ++j) acc[j] = 0.0f;
    const uint4* wr4[16];
#pragma unroll
    for (int j = 0; j < 16; ++j) wr4[j] = (const uint4*)(fcwh + (size_t)(n0 + j) * HID);

    const uint4* hq = ((const uint4*)sh) + lane * ROWQ;
#pragma unroll 2
    for (int q = 0; q < 64; ++q) {
        uint4 hp = hq[q];
#pragma unroll
        for (int j = 0; j < 16; ++j) {
            uint4 wq = wr4[j][q];
            acc[j] = dot2_(hp.x, wq.x, acc[j]); acc[j] = dot2_(hp.y, wq.y, acc[j]);
            acc[j] = dot2_(hp.z, wq.z, acc[j]); acc[j] = dot2_(hp.w, wq.w, acc[j]);
        }
    }
    __syncthreads();   // all reads of sh done

    float* so = (float*)sh;          // [64][65] padded
#pragma unroll
    for (int j = 0; j < 16; ++j) so[lane * 65 + w * 16 + j] = acc[j] + fcb[n0 + j];
    __syncthreads();

    for (int i = tid; i < 4096; i += 256) {
        int b = i >> 6, n = i & 63;
        out[((size_t)b * SEQ + t) * NSK + nt * 64 + n] = sigmoidf_(so[b * 65 + n]);
    }
}

extern "C" void kernel_launch(void* const* d_in, const int* in_sizes, int n_in,
                              void* d_out, int out_size, void* d_ws, size_t ws_size,
                              hipStream_t stream) {
    (void)in_sizes; (void)n_in; (void)out_size; (void)ws_size;

    const int*   skills   = (const int*)d_in[0];
    const int*   corrects = (const int*)d_in[1];
    const float* Wih0 = (const float*)d_in[2];
    const float* Whh0 = (const float*)d_in[3];
    const float* bih0 = (const float*)d_in[4];
    const float* bhh0 = (const float*)d_in[5];
    const float* Wih1 = (const float*)d_in[6];
    const float* Whh1 = (const float*)d_in[7];
    const float* bih1 = (const float*)d_in[8];
    const float* bhh1 = (const float*)d_in[9];
    const float* fcW  = (const float*)d_in[10];
    const float* fcb  = (const float*)d_in[11];

    char* ws = (char*)d_ws;
    half_t* h1    = (half_t*)(ws + H1_OFF);
    half_t* h2    = (half_t*)(ws + H2_OFF);
    float*  b0    = (float*)(ws + B0_OFF);
    float*  b1    = (float*)(ws + B1_OFF);
    half_t* whh0h = (half_t*)(ws + WHH0_OFF);
    half_t* wih1h = (half_t*)(ws + WIH1_OFF);
    half_t* whh1h = (half_t*)(ws + WHH1_OFF);
    half_t* fcwh  = (half_t*)(ws + FCW_OFF);
    u32*    flags = (u32*)(ws + FLG_OFF);

    prep_kernel<<<4096, 256, 0, stream>>>(Whh0, Wih1, Whh1, fcW, bih0, bhh0,
                                          bih1, bhh1, whh0h, wih1h, whh1h, fcwh,
                                          b0, b1, flags);

    PArgs pa;
    pa.skills = skills; pa.corrects = corrects; pa.Wih0 = Wih0;
    pa.Whh0 = whh0h; pa.Wih1 = wih1h; pa.Whh1 = whh1h;
    pa.b0 = b0; pa.b1 = b1; pa.h1 = h1; pa.h2 = h2;
    pa.arrive = flags; pa.go = flags + 512;

    lstm_persist<<<512, 256, 0, stream>>>(pa);

    proj_kernel<<<8192, 256, 0, stream>>>(h2, fcwh, fcb, (float*)d_out);
}

// Round 3
// 5319.797 us; speedup vs baseline: 3.5215x; 3.5215x over previous
//
#include <hip/hip_runtime.h>
#include <hip/hip_fp16.h>

typedef _Float16 f16;
typedef unsigned int u32;
typedef unsigned long long u64;
typedef _Float16 f16x4 __attribute__((ext_vector_type(4)));
typedef _Float16 f16x8 __attribute__((ext_vector_type(8)));
typedef float f32x16 __attribute__((ext_vector_type(16)));

#define SEQ   512
#define HID   512
#define NSK   1024
#define INDIM 2048
#define G4    2048
#define NWG   64
#define TWORDS 8192   // u64 words per timestep (64 KB): word = [u>>2]*64 + b

// ---- workspace layout (bytes) ----
#define H1_OFF    0ull
#define H2_OFF    33554432ull
#define WHH0_OFF  67108864ull
#define WIH1_OFF  69206016ull
#define WHH1_OFF  71303168ull
#define FCW_OFF   73400320ull
#define B0_OFF    74448896ull
#define B1_OFF    74457088ull
#define FLG_OFF   74465280ull

__device__ __forceinline__ float sigmoidf_(float x) {
    return 1.0f / (1.0f + __expf(-x));
}
__device__ __forceinline__ float tanhf_(float x) {
    return 2.0f * sigmoidf_(2.0f * x) - 1.0f;
}

// per-access coherent (sc0 sc1) ops — NO fences, NO cache flushes
__device__ __forceinline__ u64 cload(const u64* p) {
    return __hip_atomic_load(p, __ATOMIC_RELAXED, __HIP_MEMORY_SCOPE_AGENT);
}
__device__ __forceinline__ void cstore(u64* p, u64 v) {
    __hip_atomic_store(p, v, __ATOMIC_RELAXED, __HIP_MEMORY_SCOPE_AGENT);
}

__device__ __forceinline__ float dot2_(u32 a, u32 b, float c) {
    typedef _Float16 h2t __attribute__((ext_vector_type(2)));
    h2t ha = __builtin_bit_cast(h2t, a);
    h2t hb = __builtin_bit_cast(h2t, b);
#if __has_builtin(__builtin_amdgcn_fdot2)
    return __builtin_amdgcn_fdot2(ha, hb, c, false);
#else
    return c + (float)ha[0] * (float)hb[0] + (float)ha[1] * (float)hb[1];
#endif
}

// ---- prep: f16 weight copies + fused biases + flag zeroing ----
__global__ __launch_bounds__(256) void prep_kernel(
    const float* __restrict__ Whh0, const float* __restrict__ Wih1,
    const float* __restrict__ Whh1, const float* __restrict__ fcW,
    const float* __restrict__ bih0, const float* __restrict__ bhh0,
    const float* __restrict__ bih1, const float* __restrict__ bhh1,
    f16* __restrict__ whh0h, f16* __restrict__ wih1h,
    f16* __restrict__ whh1h, f16* __restrict__ fcwh,
    float* __restrict__ b0, float* __restrict__ b1, u32* __restrict__ flags)
{
    int i = blockIdx.x * 256 + threadIdx.x;
    if (i < G4 * HID) {
        whh0h[i] = (f16)Whh0[i];
        wih1h[i] = (f16)Wih1[i];
        whh1h[i] = (f16)Whh1[i];
    }
    if (i < NSK * HID) fcwh[i] = (f16)fcW[i];
    if (i < G4) { b0[i] = bih0[i] + bhh0[i]; b1[i] = bih1[i] + bhh1[i]; }
    if (i < 256) flags[i] = 0;
}

struct PArgs {
    const int* skills; const int* corrects;
    const float* Wih0;
    const f16* Whh0; const f16* Wih1; const f16* Whh1;
    const float* b0; const float* b1;
    u64* h1; u64* h2;
    u32* arrive;
};

// ---- persistent MFMA 2-layer LSTM: 64 WGs (1/CU), fence-free flag sync ----
// WG owns units [wg*8, wg*8+8) of BOTH layers (32 gate rows each).
// Wave w: ki = w&1 (K-half of the 512-dot), mi = w>>1 (batch half).
// All B (weight) fragments live in VGPRs for the whole kernel.
__global__ __launch_bounds__(256, 1) void lstm_mfma(PArgs a) {
    __shared__ float ex[2 * 2 * 64 * 33];   // [layer*2+ki][m=batch][n(pad 33)]
    __shared__ float bsh[64];               // [layer][n]: fused bias for our rows

    const int wg   = blockIdx.x;
    const int tid  = threadIdx.x;
    const int lane = tid & 63;
    const int w    = tid >> 6;
    const int ki   = w & 1;
    const int mi   = w >> 1;
    const int u0   = wg * 8;
    const int n    = lane & 31;          // B col / C col (gate-row local)
    const int nh   = lane >> 5;          // k-subblock within fragment
    const int rown = (n >> 3) * HID + u0 + (n & 7);   // weight row for col n
    const int mrow = mi * 32 + (lane & 31);           // batch row for A frags

    if (tid < 64) {
        int l = tid >> 5, nn = tid & 31;
        const float* bb = l ? a.b1 : a.b0;
        bsh[tid] = bb[(nn >> 3) * HID + u0 + (nn & 7)];
    }

    // ---- preload all B fragments (plain cached loads; weights are constant) ----
    f16x8 Bhh0[16], Bih1[16], Bhh1[16];
#pragma unroll
    for (int f = 0; f < 16; ++f) {
        int k = ki * 256 + f * 16 + nh * 8;
        Bhh0[f] = *(const f16x8*)(a.Whh0 + (size_t)rown * HID + k);
        Bih1[f] = *(const f16x8*)(a.Wih1 + (size_t)rown * HID + k);
        Bhh1[f] = *(const f16x8*)(a.Whh1 + (size_t)rown * HID + k);
    }

    float cst[8];
#pragma unroll
    for (int j = 0; j < 8; ++j) cst[j] = 0.0f;

    __syncthreads();

    for (int tau = 0; tau <= SEQ; ++tau) {
        const bool l0 = (tau < SEQ);     // layer0 computes step tau
        const bool l1 = (tau >= 1);      // layer1 computes step tau-1

        // layer0 x-term: gather one Wih0 column (wave0, lane = batch)
        float gv[32];
        bool hg = false;
        if (w == 0 && l0) {
            int sk = a.skills[lane * SEQ + tau];
            int co = a.corrects[lane * SEQ + tau];
            if (sk >= 0) {
                int xidx = sk + NSK * ((co == 1) ? 0 : 1);
                hg = true;
#pragma unroll
                for (int j = 0; j < 32; ++j) {
                    int r = (j >> 3) * HID + u0 + (j & 7);
                    gv[j] = a.Wih0[(size_t)r * INDIM + xidx];
                }
            }
        }
        if (!hg) {
#pragma unroll
            for (int j = 0; j < 32; ++j) gv[j] = 0.0f;
        }

        // ---- A fragments straight from IF$ (coherent 8B loads) ----
        union AF { u64 d[2]; f16x8 v; };
        AF a1[16], a2[16];
        if (l1) {
            const u64* h1p = a.h1 + (size_t)(tau - 1) * TWORDS;
#pragma unroll
            for (int f = 0; f < 16; ++f) {
                int ch = ki * 64 + f * 4 + nh * 2;    // k>>2 chunk
                int idx = ch * 64 + mrow;
                a1[f].d[0] = cload(h1p + idx);
                a1[f].d[1] = cload(h1p + idx + 64);
            }
        }
        if (tau >= 2) {
            const u64* h2p = a.h2 + (size_t)(tau - 2) * TWORDS;
#pragma unroll
            for (int f = 0; f < 16; ++f) {
                int ch = ki * 64 + f * 4 + nh * 2;
                int idx = ch * 64 + mrow;
                a2[f].d[0] = cload(h2p + idx);
                a2[f].d[1] = cload(h2p + idx + 64);
            }
        }

        f32x16 accA, accB;
#pragma unroll
        for (int j = 0; j < 16; ++j) { accA[j] = 0.0f; accB[j] = 0.0f; }

        if (l1) {
            if (l0) {
#pragma unroll
                for (int f = 0; f < 16; ++f)
                    accA = __builtin_amdgcn_mfma_f32_32x32x16_f16(a1[f].v, Bhh0[f], accA, 0, 0, 0);
            }
#pragma unroll
            for (int f = 0; f < 16; ++f)
                accB = __builtin_amdgcn_mfma_f32_32x32x16_f16(a1[f].v, Bih1[f], accB, 0, 0, 0);
        }
        if (tau >= 2) {
#pragma unroll
            for (int f = 0; f < 16; ++f)
                accB = __builtin_amdgcn_mfma_f32_32x32x16_f16(a2[f].v, Bhh1[f], accB, 0, 0, 0);
        }

        // ---- gate exchange (sum K-halves) ----
        __syncthreads();    // previous tick's ex readers done
#pragma unroll
        for (int r = 0; r < 16; ++r) {
            int mr = (r & 3) + 8 * (r >> 2) + 4 * nh;   // C/D row mapping (32x32)
            int m = mi * 32 + mr;
            ex[(ki * 64 + m) * 33 + n] = accA[r];
            ex[((2 + ki) * 64 + m) * 33 + n] = accB[r];
        }
        __syncthreads();

        // ---- cell update: wave0 -> layer0, wave1 -> layer1; lane = batch ----
        if (w < 2 && ((w == 0) ? l0 : l1)) {
            const int t = (w == 0) ? tau : tau - 1;
            const int s0b = (w * 2 + 0) * 64 + lane;
            const int s1b = (w * 2 + 1) * 64 + lane;
            f16 hh[8];
#pragma unroll
            for (int uu = 0; uu < 8; ++uu) {
                float gi = ex[s0b * 33 + uu]      + ex[s1b * 33 + uu]      + bsh[w * 32 + uu];
                float gf = ex[s0b * 33 + 8 + uu]  + ex[s1b * 33 + 8 + uu]  + bsh[w * 32 + 8 + uu];
                float gg = ex[s0b * 33 + 16 + uu] + ex[s1b * 33 + 16 + uu] + bsh[w * 32 + 16 + uu];
                float go = ex[s0b * 33 + 24 + uu] + ex[s1b * 33 + 24 + uu] + bsh[w * 32 + 24 + uu];
                if (w == 0) { gi += gv[uu]; gf += gv[8 + uu]; gg += gv[16 + uu]; go += gv[24 + uu]; }
                float c_ = (t > 0) ? cst[uu] : 0.0f;
                float cn = sigmoidf_(gf) * c_ + sigmoidf_(gi) * tanhf_(gg);
                float hv = sigmoidf_(go) * tanhf_(cn);
                cst[uu] = cn;
                hh[uu] = (f16)hv;
            }
            union HP { f16x4 h; u64 d; } p0, p1;
            p0.h = (f16x4){hh[0], hh[1], hh[2], hh[3]};
            p1.h = (f16x4){hh[4], hh[5], hh[6], hh[7]};
            u64* hb = (w == 0) ? (a.h1 + (size_t)t * TWORDS) : (a.h2 + (size_t)t * TWORDS);
            cstore(hb + (size_t)(wg * 2 + 0) * 64 + lane, p0.d);
            cstore(hb + (size_t)(wg * 2 + 1) * 64 + lane, p1.d);
        }

        // ---- fence-free barrier: syncthreads drains vmcnt => stores visible ----
        __syncthreads();
        if (tid == 0)
            __hip_atomic_store(&a.arrive[wg], (u32)(tau + 1), __ATOMIC_RELAXED,
                               __HIP_MEMORY_SCOPE_AGENT);
        if (w == 0 && tau < SEQ) {
            const u32 want = (u32)(tau + 1);
            int guard = 0;
            while (true) {
                u32 v = __hip_atomic_load(&a.arrive[lane], __ATOMIC_RELAXED,
                                          __HIP_MEMORY_SCOPE_AGENT);
                if (__ballot(v < want) == 0ull) break;
                __builtin_amdgcn_s_sleep(1);
                if (++guard > (1 << 20)) break;   // visible failure, never hang
            }
        }
        __syncthreads();
    }
}

// ---- projection: out[b][t][n] = sigmoid(h2[t][b][:] . fcW[n] + fcb[n]) ----
__global__ __launch_bounds__(256) void proj_kernel(
    const u64* __restrict__ h2, const f16* __restrict__ fcwh,
    const float* __restrict__ fcb, float* __restrict__ out)
{
    __shared__ u64 sh[64 * 130];   // [b][u4] padded; reused as f32 [64][65] stage

    const int t = blockIdx.x >> 4;
    const int nt = blockIdx.x & 15;
    const int tid = threadIdx.x;
    const int lane = tid & 63;     // batch
    const int w = tid >> 6;

    const u64* src = h2 + (size_t)t * TWORDS;
    for (int i = tid; i < TWORDS; i += 256) {
        int u4 = i >> 6, b = i & 63;
        sh[b * 130 + u4] = src[i];
    }
    __syncthreads();

    const int n0 = nt * 64 + w * 16;
    float acc[16];
#pragma unroll
    for (int j = 0; j < 16; ++j) acc[j] = 0.0f;
    const uint4* wr4[16];
#pragma unroll
    for (int j = 0; j < 16; ++j) wr4[j] = (const uint4*)(fcwh + (size_t)(n0 + j) * HID);

    const uint4* hq = (const uint4*)(sh + (size_t)lane * 130);
#pragma unroll 2
    for (int q = 0; q < 64; ++q) {
        uint4 hp = hq[q];
#pragma unroll
        for (int j = 0; j < 16; ++j) {
            uint4 wq = wr4[j][q];
            acc[j] = dot2_(hp.x, wq.x, acc[j]); acc[j] = dot2_(hp.y, wq.y, acc[j]);
            acc[j] = dot2_(hp.z, wq.z, acc[j]); acc[j] = dot2_(hp.w, wq.w, acc[j]);
        }
    }
    __syncthreads();

    float* so = (float*)sh;        // [64][65]
#pragma unroll
    for (int j = 0; j < 16; ++j) so[lane * 65 + w * 16 + j] = acc[j] + fcb[n0 + j];
    __syncthreads();

    for (int i = tid; i < 4096; i += 256) {
        int b = i >> 6, nn = i & 63;
        out[((size_t)b * SEQ + t) * NSK + nt * 64 + nn] = sigmoidf_(so[b * 65 + nn]);
    }
}

extern "C" void kernel_launch(void* const* d_in, const int* in_sizes, int n_in,
                              void* d_out, int out_size, void* d_ws, size_t ws_size,
                              hipStream_t stream) {
    (void)in_sizes; (void)n_in; (void)out_size; (void)ws_size;

    const int*   skills   = (const int*)d_in[0];
    const int*   corrects = (const int*)d_in[1];
    const float* Wih0 = (const float*)d_in[2];
    const float* Whh0 = (const float*)d_in[3];
    const float* bih0 = (const float*)d_in[4];
    const float* bhh0 = (const float*)d_in[5];
    const float* Wih1 = (const float*)d_in[6];
    const float* Whh1 = (const float*)d_in[7];
    const float* bih1 = (const float*)d_in[8];
    const float* bhh1 = (const float*)d_in[9];
    const float* fcW  = (const float*)d_in[10];
    const float* fcb  = (const float*)d_in[11];

    char* ws = (char*)d_ws;
    u64*  h1    = (u64*)(ws + H1_OFF);
    u64*  h2    = (u64*)(ws + H2_OFF);
    f16*  whh0h = (f16*)(ws + WHH0_OFF);
    f16*  wih1h = (f16*)(ws + WIH1_OFF);
    f16*  whh1h = (f16*)(ws + WHH1_OFF);
    f16*  fcwh  = (f16*)(ws + FCW_OFF);
    float* b0   = (float*)(ws + B0_OFF);
    float* b1   = (float*)(ws + B1_OFF);
    u32*  flags = (u32*)(ws + FLG_OFF);

    prep_kernel<<<4096, 256, 0, stream>>>(Whh0, Wih1, Whh1, fcW, bih0, bhh0,
                                          bih1, bhh1, whh0h, wih1h, whh1h, fcwh,
                                          b0, b1, flags);

    PArgs pa;
    pa.skills = skills; pa.corrects = corrects; pa.Wih0 = Wih0;
    pa.Whh0 = whh0h; pa.Wih1 = wih1h; pa.Whh1 = whh1h;
    pa.b0 = b0; pa.b1 = b1; pa.h1 = h1; pa.h2 = h2;
    pa.arrive = flags;

    lstm_mfma<<<NWG, 256, 0, stream>>>(pa);

    proj_kernel<<<8192, 256, 0, stream>>>(h2, fcwh, fcb, (float*)d_out);
}

// Round 4
// 4619.680 us; speedup vs baseline: 4.0551x; 1.1516x over previous
//
#include <hip/hip_runtime.h>
#include <hip/hip_fp16.h>

typedef _Float16 f16;
typedef unsigned int u32;
typedef unsigned long long u64;
typedef _Float16 f16x4 __attribute__((ext_vector_type(4)));
typedef _Float16 f16x8 __attribute__((ext_vector_type(8)));
typedef float f32x16 __attribute__((ext_vector_type(16)));

#define SEQ   512
#define HID   512
#define NSK   1024
#define INDIM 2048
#define G4    2048
#define NWG   64
#define TWORDS 8192   // u64 words per timestep: word = ug*128 + b*2 + p (ug=u>>3, p=(u>>2)&1)

// ---- workspace layout (bytes) ----
#define H1_OFF    0ull
#define H2_OFF    33554432ull
#define WHH0_OFF  67108864ull
#define WIH1_OFF  69206016ull
#define WHH1_OFF  71303168ull
#define FCW_OFF   73400320ull
#define B0_OFF    74448896ull
#define B1_OFF    74457088ull
#define W0P_OFF   74465280ull   // 8 MB: [2048 col][64 wg][32 j]  f16, j = gate*8 + unit
#define FLG_OFF   82853888ull

__device__ __forceinline__ float sigmoidf_(float x) {
    return 1.0f / (1.0f + __expf(-x));
}
__device__ __forceinline__ float tanhf_(float x) {
    return 2.0f * sigmoidf_(2.0f * x) - 1.0f;
}

// per-access coherent (sc0 sc1) ops — NO fences, NO cache flushes (R2 lesson)
__device__ __forceinline__ u64 cload(const u64* p) {
    return __hip_atomic_load(p, __ATOMIC_RELAXED, __HIP_MEMORY_SCOPE_AGENT);
}
__device__ __forceinline__ void cstore(u64* p, u64 v) {
    __hip_atomic_store(p, v, __ATOMIC_RELAXED, __HIP_MEMORY_SCOPE_AGENT);
}

__device__ __forceinline__ float dot2_(u32 a, u32 b, float c) {
    typedef _Float16 h2t __attribute__((ext_vector_type(2)));
    h2t ha = __builtin_bit_cast(h2t, a);
    h2t hb = __builtin_bit_cast(h2t, b);
#if __has_builtin(__builtin_amdgcn_fdot2)
    return __builtin_amdgcn_fdot2(ha, hb, c, false);
#else
    return c + (float)ha[0] * (float)hb[0] + (float)ha[1] * (float)hb[1];
#endif
}

// ---- prep: f16 weight copies + fused biases + flag zeroing ----
__global__ __launch_bounds__(256) void prep_kernel(
    const float* __restrict__ Whh0, const float* __restrict__ Wih1,
    const float* __restrict__ Whh1, const float* __restrict__ fcW,
    const float* __restrict__ bih0, const float* __restrict__ bhh0,
    const float* __restrict__ bih1, const float* __restrict__ bhh1,
    f16* __restrict__ whh0h, f16* __restrict__ wih1h,
    f16* __restrict__ whh1h, f16* __restrict__ fcwh,
    float* __restrict__ b0, float* __restrict__ b1, u32* __restrict__ flags)
{
    int i = blockIdx.x * 256 + threadIdx.x;
    if (i < G4 * HID) {
        whh0h[i] = (f16)Whh0[i];
        wih1h[i] = (f16)Wih1[i];
        whh1h[i] = (f16)Whh1[i];
    }
    if (i < NSK * HID) fcwh[i] = (f16)fcW[i];
    if (i < G4) { b0[i] = bih0[i] + bhh0[i]; b1[i] = bih1[i] + bhh1[i]; }
    if (i < NWG) flags[i] = 0;
}

// ---- W0P build: W0P[c][wg][j] = Wih0[r][c], r = (j>>3)*512 + wg*8 + (j&7) ----
__global__ __launch_bounds__(256) void w0p_kernel(
    const float* __restrict__ Wih0, f16* __restrict__ w0p)
{
    __shared__ float tl[64][65];
    const int tid = threadIdx.x;
    const int ct = blockIdx.x & 31, rt = blockIdx.x >> 5;
    const int r0 = rt * 64, c0 = ct * 64;
#pragma unroll 4
    for (int i = 0; i < 16; ++i) {
        int rr = i * 4 + (tid >> 6);
        int cc = tid & 63;
        tl[rr][cc] = Wih0[(size_t)(r0 + rr) * INDIM + c0 + cc];
    }
    __syncthreads();
    const int jh = r0 >> 9;            // gate (const in tile)
    const int wg0 = (r0 & 511) >> 3;   // first wg chunk
    for (int task = tid; task < 512; task += 256) {
        int c = task >> 3, wgl = task & 7;
        f16 tmp[8];
#pragma unroll
        for (int jl = 0; jl < 8; ++jl) tmp[jl] = (f16)tl[wgl * 8 + jl][c];
        *(f16x8*)&w0p[(size_t)(c0 + c) * 2048 + (wg0 + wgl) * 32 + jh * 8] =
            *(f16x8*)tmp;
    }
}

struct PArgs {
    const int* skills; const int* corrects;
    const f16* W0P;
    const f16* Whh0; const f16* Wih1; const f16* Whh1;
    const float* b0; const float* b1;
    u64* h1; u64* h2;
    u32* arrive;
};

// ---- persistent MFMA 2-layer LSTM: 64 WGs (1/CU), fence-free flag sync ----
// WG owns units [wg*8, wg*8+8) of BOTH layers (32 gate rows each).
// MFMA role: ki = w&1 (K-half), mi = w>>1 (batch half). All B frags in VGPRs.
// Cell role: waves 0,1 -> layer0 (q=w), waves 2,3 -> layer1 (q=w&1); lane=batch,
//            each lane updates units u0 + q*4 .. +3.
__global__ __launch_bounds__(256, 1) void lstm_mfma(PArgs a) {
    __shared__ float ex[2 * 2 * 64 * 33];   // [(layer*2+ki)][m=batch][n(pad 33)]
    __shared__ float bsh[64];               // [layer][n 0..31]

    const int wg   = blockIdx.x;
    const int tid  = threadIdx.x;
    const int lane = tid & 63;
    const int w    = tid >> 6;
    const int ki   = w & 1;
    const int mi   = w >> 1;
    const int u0   = wg * 8;
    const int n    = lane & 31;
    const int nh   = lane >> 5;
    const int rown = (n >> 3) * HID + u0 + (n & 7);
    const int mrow = mi * 32 + (lane & 31);
    const int lyr  = w >> 1;               // cell layer
    const int q    = w & 1;                // cell unit-quad

    if (tid < 64) {
        int l = tid >> 5, nn = tid & 31;
        const float* bb = l ? a.b1 : a.b0;
        bsh[tid] = bb[(nn >> 3) * HID + u0 + (nn & 7)];
    }

    // ---- preload all B fragments ----
    f16x8 Bhh0[16], Bih1[16], Bhh1[16];
#pragma unroll
    for (int f = 0; f < 16; ++f) {
        int k = ki * 256 + f * 16 + nh * 8;
        Bhh0[f] = *(const f16x8*)(a.Whh0 + (size_t)rown * HID + k);
        Bih1[f] = *(const f16x8*)(a.Wih1 + (size_t)rown * HID + k);
        Bhh1[f] = *(const f16x8*)(a.Whh1 + (size_t)rown * HID + k);
    }

    float cst[4];
#pragma unroll
    for (int j = 0; j < 4; ++j) cst[j] = 0.0f;

    // idx prefetch for tau=0 (cell waves of layer0 need it)
    int idx_nxt = -1;
    if (w < 2) {
        int sk = a.skills[lane * SEQ + 0];
        int co = a.corrects[lane * SEQ + 0];
        idx_nxt = (sk >= 0) ? sk + NSK * ((co == 1) ? 0 : 1) : -1;
    }

    __syncthreads();

    for (int tau = 0; tau <= SEQ; ++tau) {
        const bool l0 = (tau < SEQ);
        const bool l1 = (tau >= 1);
        const int idx_cur = idx_nxt;

        // ---- issue x-gather early (waves 0,1; consumed at cell update) ----
        uint2 gq[4];
        if (w < 2 && l0) {
            if (idx_cur >= 0) {
                const uint2* gp =
                    (const uint2*)(a.W0P + (size_t)idx_cur * 2048 + wg * 32 + q * 4);
#pragma unroll
                for (int gg = 0; gg < 4; ++gg) gq[gg] = gp[gg * 2];  // gate stride 8 f16
            } else {
#pragma unroll
                for (int gg = 0; gg < 4; ++gg) gq[gg] = (uint2){0u, 0u};
            }
            if (tau + 1 < SEQ) {
                int sk = a.skills[lane * SEQ + tau + 1];
                int co = a.corrects[lane * SEQ + tau + 1];
                idx_nxt = (sk >= 0) ? sk + NSK * ((co == 1) ? 0 : 1) : -1;
            }
        }

        // ---- A fragments from IF$ (coherent 8B pairs, same line) ----
        union AF { u64 d[2]; f16x8 v; };
        AF a1[16], a2[16];
        if (l1) {
            const u64* h1p = a.h1 + (size_t)(tau - 1) * TWORDS;
#pragma unroll
            for (int f = 0; f < 16; ++f) {
                int base = (ki * 32 + f * 2 + nh) * 128 + mrow * 2;
                a1[f].d[0] = cload(h1p + base);
                a1[f].d[1] = cload(h1p + base + 1);
            }
        }
        if (tau >= 2) {
            const u64* h2p = a.h2 + (size_t)(tau - 2) * TWORDS;
#pragma unroll
            for (int f = 0; f < 16; ++f) {
                int base = (ki * 32 + f * 2 + nh) * 128 + mrow * 2;
                a2[f].d[0] = cload(h2p + base);
                a2[f].d[1] = cload(h2p + base + 1);
            }
        }

        f32x16 accA, accB;
#pragma unroll
        for (int j = 0; j < 16; ++j) { accA[j] = 0.0f; accB[j] = 0.0f; }

        if (l1) {
            if (l0) {
#pragma unroll
                for (int f = 0; f < 16; ++f)
                    accA = __builtin_amdgcn_mfma_f32_32x32x16_f16(a1[f].v, Bhh0[f], accA, 0, 0, 0);
            }
#pragma unroll
            for (int f = 0; f < 16; ++f)
                accB = __builtin_amdgcn_mfma_f32_32x32x16_f16(a1[f].v, Bih1[f], accB, 0, 0, 0);
        }
        if (tau >= 2) {
#pragma unroll
            for (int f = 0; f < 16; ++f)
                accB = __builtin_amdgcn_mfma_f32_32x32x16_f16(a2[f].v, Bhh1[f], accB, 0, 0, 0);
        }

        // ---- gate exchange (no leading sync: loop-end barrier covers it) ----
#pragma unroll
        for (int r = 0; r < 16; ++r) {
            int m = mi * 32 + (r & 3) + 8 * (r >> 2) + 4 * nh;
            ex[(ki * 64 + m) * 33 + n] = accA[r];
            ex[((2 + ki) * 64 + m) * 33 + n] = accB[r];
        }
        __syncthreads();

        // ---- cell update: all 4 waves; lane=batch, 4 units each ----
        const bool cact = lyr ? l1 : l0;
        if (cact) {
            const int t = lyr ? tau - 1 : tau;
            const float* e0 = ex + (lyr * 2 + 0) * (64 * 33) + lane * 33;
            const float* e1 = ex + (lyr * 2 + 1) * (64 * 33) + lane * 33;
            f16 hh[4];
            f16x4 gx = (f16x4){0, 0, 0, 0};
#pragma unroll
            for (int uu = 0; uu < 4; ++uu) {
                int nc = q * 4 + uu;
                float gi = e0[nc]      + e1[nc]      + bsh[lyr * 32 + nc];
                float gf = e0[8 + nc]  + e1[8 + nc]  + bsh[lyr * 32 + 8 + nc];
                float gg = e0[16 + nc] + e1[16 + nc] + bsh[lyr * 32 + 16 + nc];
                float go = e0[24 + nc] + e1[24 + nc] + bsh[lyr * 32 + 24 + nc];
                if (lyr == 0) {
                    f16x4 xi = __builtin_bit_cast(f16x4, gq[0]);
                    f16x4 xf = __builtin_bit_cast(f16x4, gq[1]);
                    f16x4 xg = __builtin_bit_cast(f16x4, gq[2]);
                    f16x4 xo = __builtin_bit_cast(f16x4, gq[3]);
                    gi += (float)xi[uu]; gf += (float)xf[uu];
                    gg += (float)xg[uu]; go += (float)xo[uu];
                }
                float c_ = (t > 0) ? cst[uu] : 0.0f;
                float cn = sigmoidf_(gf) * c_ + sigmoidf_(gi) * tanhf_(gg);
                float hv = sigmoidf_(go) * tanhf_(cn);
                cst[uu] = cn;
                hh[uu] = (f16)hv;
            }
            (void)gx;
            union HP { f16x4 h; u64 d; } p;
            p.h = (f16x4){hh[0], hh[1], hh[2], hh[3]};
            u64* hb = lyr ? (a.h2 + (size_t)t * TWORDS) : (a.h1 + (size_t)t * TWORDS);
            cstore(hb + (size_t)wg * 128 + lane * 2 + q, p.d);
        }

        // ---- barrier: sync drains stores; all waves poll in parallel ----
        __syncthreads();
        if (tid == 0)
            __hip_atomic_store(&a.arrive[wg], (u32)(tau + 1), __ATOMIC_RELAXED,
                               __HIP_MEMORY_SCOPE_AGENT);
        if (tau < SEQ) {
            const u32 want = (u32)(tau + 1);
            int guard = 0;
            while (true) {
                u32 v = __hip_atomic_load(&a.arrive[lane], __ATOMIC_RELAXED,
                                          __HIP_MEMORY_SCOPE_AGENT);
                if (__ballot(v < want) == 0ull) break;
                __builtin_amdgcn_s_sleep(1);
                if (++guard > (1 << 20)) break;   // visible failure, never hang
            }
        }
    }
}

// ---- projection: out[b][t][n] = sigmoid(h2[t][b][:] . fcW[n] + fcb[n]) ----
__global__ __launch_bounds__(256) void proj_kernel(
    const u64* __restrict__ h2, const f16* __restrict__ fcwh,
    const float* __restrict__ fcb, float* __restrict__ out)
{
    __shared__ u64 sh[64 * 130];   // [b][ug*2+p] padded; reused as f32 [64][65]

    const int t = blockIdx.x >> 4;
    const int nt = blockIdx.x & 15;
    const int tid = threadIdx.x;
    const int lane = tid & 63;     // batch
    const int w = tid >> 6;

    const u64* src = h2 + (size_t)t * TWORDS;
    for (int i = tid; i < TWORDS; i += 256) {
        int ug = i >> 7, rem = i & 127;
        int b = rem >> 1, p = rem & 1;
        sh[b * 130 + ug * 2 + p] = src[i];
    }
    __syncthreads();

    const int n0 = nt * 64 + w * 16;
    float acc[16];
#pragma unroll
    for (int j = 0; j < 16; ++j) acc[j] = 0.0f;
    const uint4* wr4[16];
#pragma unroll
    for (int j = 0; j < 16; ++j) wr4[j] = (const uint4*)(fcwh + (size_t)(n0 + j) * HID);

    const uint4* hq = (const uint4*)(sh + (size_t)lane * 130);
#pragma unroll 2
    for (int qq = 0; qq < 64; ++qq) {
        uint4 hp = hq[qq];
#pragma unroll
        for (int j = 0; j < 16; ++j) {
            uint4 wq = wr4[j][qq];
            acc[j] = dot2_(hp.x, wq.x, acc[j]); acc[j] = dot2_(hp.y, wq.y, acc[j]);
            acc[j] = dot2_(hp.z, wq.z, acc[j]); acc[j] = dot2_(hp.w, wq.w, acc[j]);
        }
    }
    __syncthreads();

    float* so = (float*)sh;        // [64][65]
#pragma unroll
    for (int j = 0; j < 16; ++j) so[lane * 65 + w * 16 + j] = acc[j] + fcb[n0 + j];
    __syncthreads();

    for (int i = tid; i < 4096; i += 256) {
        int b = i >> 6, nn = i & 63;
        out[((size_t)b * SEQ + t) * NSK + nt * 64 + nn] = sigmoidf_(so[b * 65 + nn]);
    }
}

extern "C" void kernel_launch(void* const* d_in, const int* in_sizes, int n_in,
                              void* d_out, int out_size, void* d_ws, size_t ws_size,
                              hipStream_t stream) {
    (void)in_sizes; (void)n_in; (void)out_size; (void)ws_size;

    const int*   skills   = (const int*)d_in[0];
    const int*   corrects = (const int*)d_in[1];
    const float* Wih0 = (const float*)d_in[2];
    const float* Whh0 = (const float*)d_in[3];
    const float* bih0 = (const float*)d_in[4];
    const float* bhh0 = (const float*)d_in[5];
    const float* Wih1 = (const float*)d_in[6];
    const float* Whh1 = (const float*)d_in[7];
    const float* bih1 = (const float*)d_in[8];
    const float* bhh1 = (const float*)d_in[9];
    const float* fcW  = (const float*)d_in[10];
    const float* fcb  = (const float*)d_in[11];

    char* ws = (char*)d_ws;
    u64*  h1    = (u64*)(ws + H1_OFF);
    u64*  h2    = (u64*)(ws + H2_OFF);
    f16*  whh0h = (f16*)(ws + WHH0_OFF);
    f16*  wih1h = (f16*)(ws + WIH1_OFF);
    f16*  whh1h = (f16*)(ws + WHH1_OFF);
    f16*  fcwh  = (f16*)(ws + FCW_OFF);
    float* b0   = (float*)(ws + B0_OFF);
    float* b1   = (float*)(ws + B1_OFF);
    f16*  w0p   = (f16*)(ws + W0P_OFF);
    u32*  flags = (u32*)(ws + FLG_OFF);

    prep_kernel<<<4096, 256, 0, stream>>>(Whh0, Wih1, Whh1, fcW, bih0, bhh0,
                                          bih1, bhh1, whh0h, wih1h, whh1h, fcwh,
                                          b0, b1, flags);
    w0p_kernel<<<1024, 256, 0, stream>>>(Wih0, w0p);

    PArgs pa;
    pa.skills = skills; pa.corrects = corrects; pa.W0P = w0p;
    pa.Whh0 = whh0h; pa.Wih1 = wih1h; pa.Whh1 = whh1h;
    pa.b0 = b0; pa.b1 = b1; pa.h1 = h1; pa.h2 = h2;
    pa.arrive = flags;

    lstm_mfma<<<NWG, 256, 0, stream>>>(pa);

    proj_kernel<<<8192, 256, 0, stream>>>(h2, fcwh, fcb, (float*)d_out);
}

// Round 5
// 2677.920 us; speedup vs baseline: 6.9955x; 1.7251x over previous
//
#include <hip/hip_runtime.h>
#include <hip/hip_fp16.h>

typedef _Float16 f16;
typedef unsigned int u32;
typedef unsigned long long u64;
typedef _Float16 f16x4 __attribute__((ext_vector_type(4)));
typedef _Float16 f16x8 __attribute__((ext_vector_type(8)));
typedef float f32x4 __attribute__((ext_vector_type(4)));
typedef float f32x16 __attribute__((ext_vector_type(16)));

#define SEQ   512
#define HID   512
#define NSK   1024
#define INDIM 2048
#define G4    2048
#define NWG   64
#define TWORDS 8192   // u64 words per timestep: word = G*128 + b*2 + p  (G=u>>3, p=(u>>2)&1)

// ---- workspace layout (bytes) ----
#define H1_OFF    0ull
#define H2_OFF    33554432ull
#define WHH0_OFF  67108864ull
#define WIH1_OFF  69206016ull
#define WHH1_OFF  71303168ull
#define FCW_OFF   73400320ull
#define B0_OFF    74448896ull
#define B1_OFF    74457088ull
#define W0P_OFF   74465280ull   // 8 MB: [2048 col][64 wg][32 j]  f16, j = gate*8 + unit
#define FLG_OFF   82853888ull   // 64 flags padded to 64B each (u32 stride 16)

__device__ __forceinline__ float sigmoidf_(float x) {
    return 1.0f / (1.0f + __expf(-x));
}
__device__ __forceinline__ float tanhf_(float x) {
    return 2.0f * sigmoidf_(2.0f * x) - 1.0f;
}

// h stores: per-access write-through (sc0 sc1) so MALL holds fresh data. NO fences (R2 lesson).
__device__ __forceinline__ void cstore(u64* p, u64 v) {
    __hip_atomic_store(p, v, __ATOMIC_RELAXED, __HIP_MEMORY_SCOPE_AGENT);
}

// ---- prep: f16 weight copies + fused biases + flag zeroing ----
__global__ __launch_bounds__(256) void prep_kernel(
    const float* __restrict__ Whh0, const float* __restrict__ Wih1,
    const float* __restrict__ Whh1, const float* __restrict__ fcW,
    const float* __restrict__ bih0, const float* __restrict__ bhh0,
    const float* __restrict__ bih1, const float* __restrict__ bhh1,
    f16* __restrict__ whh0h, f16* __restrict__ wih1h,
    f16* __restrict__ whh1h, f16* __restrict__ fcwh,
    float* __restrict__ b0, float* __restrict__ b1, u32* __restrict__ flags)
{
    int i = blockIdx.x * 256 + threadIdx.x;
    if (i < G4 * HID) {
        whh0h[i] = (f16)Whh0[i];
        wih1h[i] = (f16)Wih1[i];
        whh1h[i] = (f16)Whh1[i];
    }
    if (i < NSK * HID) fcwh[i] = (f16)fcW[i];
    if (i < G4) { b0[i] = bih0[i] + bhh0[i]; b1[i] = bih1[i] + bhh1[i]; }
    if (i < NWG * 16) flags[i] = 0;
}

// ---- W0P build: W0P[c][wg][j] = Wih0[r][c], r = (j>>3)*512 + wg*8 + (j&7) ----
__global__ __launch_bounds__(256) void w0p_kernel(
    const float* __restrict__ Wih0, f16* __restrict__ w0p)
{
    __shared__ float tl[64][65];
    const int tid = threadIdx.x;
    const int ct = blockIdx.x & 31, rt = blockIdx.x >> 5;
    const int r0 = rt * 64, c0 = ct * 64;
#pragma unroll 4
    for (int i = 0; i < 16; ++i) {
        int rr = i * 4 + (tid >> 6);
        int cc = tid & 63;
        tl[rr][cc] = Wih0[(size_t)(r0 + rr) * INDIM + c0 + cc];
    }
    __syncthreads();
    const int jh = r0 >> 9;            // gate (const in tile)
    const int wg0 = (r0 & 511) >> 3;   // first wg chunk
    for (int task = tid; task < 512; task += 256) {
        int c = task >> 3, wgl = task & 7;
        f16 tmp[8];
#pragma unroll
        for (int jl = 0; jl < 8; ++jl) tmp[jl] = (f16)tl[wgl * 8 + jl][c];
        *(f16x8*)&w0p[(size_t)(c0 + c) * 2048 + (wg0 + wgl) * 32 + jh * 8] =
            *(f16x8*)tmp;
    }
}

struct PArgs {
    const int* skills; const int* corrects;
    const f16* W0P;
    const f16* Whh0; const f16* Wih1; const f16* Whh1;
    const float* b0; const float* b1;
    u64* h1; u64* h2;
    u32* arrive;   // stride-16 u32 (one 64B line per WG)
};

// ---- persistent MFMA 2-layer LSTM: 64 WGs (1/CU), fence-free flag sync ----
// WG owns units [wg*8, wg*8+8) of BOTH layers (32 gate rows each).
// MFMA role: ki = w&1 (K-half), mi = w>>1 (batch half). All B frags in VGPRs.
// Cell role: waves 0,1 -> layer0, waves 2,3 -> layer1; lane=batch, 4 units each.
// h A-loads are PLAIN cached loads (L2-served); h stores are sc1 write-through.
__global__ __launch_bounds__(256, 1) void lstm_mfma(PArgs a) {
    __shared__ float ex[2 * 2 * 64 * 33];   // [(layer*2+ki)][m=batch][n(pad 33)]
    __shared__ float bsh[64];               // [layer][n 0..31]

    const int wg   = blockIdx.x;
    const int tid  = threadIdx.x;
    const int lane = tid & 63;
    const int w    = tid >> 6;
    const int ki   = w & 1;
    const int mi   = w >> 1;
    const int u0   = wg * 8;
    const int n    = lane & 31;
    const int nh   = lane >> 5;
    const int rown = (n >> 3) * HID + u0 + (n & 7);
    const int mrow = mi * 32 + (lane & 31);
    const int lyr  = w >> 1;               // cell layer
    const int q    = w & 1;                // cell unit-quad

    if (tid < 64) {
        int l = tid >> 5, nn = tid & 31;
        const float* bb = l ? a.b1 : a.b0;
        bsh[tid] = bb[(nn >> 3) * HID + u0 + (nn & 7)];
    }

    // ---- preload all B fragments ----
    f16x8 Bhh0[16], Bih1[16], Bhh1[16];
#pragma unroll
    for (int f = 0; f < 16; ++f) {
        int k = ki * 256 + f * 16 + nh * 8;
        Bhh0[f] = *(const f16x8*)(a.Whh0 + (size_t)rown * HID + k);
        Bih1[f] = *(const f16x8*)(a.Wih1 + (size_t)rown * HID + k);
        Bhh1[f] = *(const f16x8*)(a.Whh1 + (size_t)rown * HID + k);
    }

    float cst[4];
#pragma unroll
    for (int j = 0; j < 4; ++j) cst[j] = 0.0f;

    // x-gather pipeline state (waves 0,1 only): gqn holds W0P row-chunk for the
    // CURRENT tick's cell; idxq is its validity; sraw/craw prefetch next skills.
    uint2 gq0 = {0,0}, gq1 = {0,0}, gq2 = {0,0}, gq3 = {0,0};
    int idxq = -1;
    int sraw = 0, craw = 0;
    if (w < 2) {
        int sk = a.skills[lane * SEQ + 0];
        int co = a.corrects[lane * SEQ + 0];
        idxq = (sk >= 0) ? sk + NSK * ((co == 1) ? 0 : 1) : -1;
        const uint2* gp = (const uint2*)(a.W0P +
            (size_t)((idxq >= 0) ? idxq : 0) * 2048 + wg * 32 + q * 4);
        gq0 = gp[0]; gq1 = gp[2]; gq2 = gp[4]; gq3 = gp[6];   // gate stride 8 f16
        if (SEQ > 1) {
            sraw = a.skills[lane * SEQ + 1];
            craw = a.corrects[lane * SEQ + 1];
        }
    }

    __syncthreads();

    for (int tau = 0; tau <= SEQ; ++tau) {
        const bool l0 = (tau < SEQ);
        const bool l1 = (tau >= 1);

        // ---- A fragments: plain cached loads (L2-shared across the XCD) ----
        union AF { uint4 u; f16x8 v; };
        AF a1[16], a2[16];
        if (l1) {
            const u64* __restrict__ h1p = a.h1 + (size_t)(tau - 1) * TWORDS;
#pragma unroll
            for (int f = 0; f < 16; ++f) {
                int base = (ki * 32 + f * 2 + nh) * 128 + mrow * 2;
                a1[f].u = *(const uint4*)(h1p + base);
            }
        }
        if (tau >= 2) {
            const u64* __restrict__ h2p = a.h2 + (size_t)(tau - 2) * TWORDS;
#pragma unroll
            for (int f = 0; f < 16; ++f) {
                int base = (ki * 32 + f * 2 + nh) * 128 + mrow * 2;
                a2[f].u = *(const uint4*)(h2p + base);
            }
        }

        f32x16 accA, accB;
#pragma unroll
        for (int j = 0; j < 16; ++j) { accA[j] = 0.0f; accB[j] = 0.0f; }

        if (l1) {
            if (l0) {
#pragma unroll
                for (int f = 0; f < 16; ++f)
                    accA = __builtin_amdgcn_mfma_f32_32x32x16_f16(a1[f].v, Bhh0[f], accA, 0, 0, 0);
            }
#pragma unroll
            for (int f = 0; f < 16; ++f)
                accB = __builtin_amdgcn_mfma_f32_32x32x16_f16(a1[f].v, Bih1[f], accB, 0, 0, 0);
        }
        if (tau >= 2) {
#pragma unroll
            for (int f = 0; f < 16; ++f)
                accB = __builtin_amdgcn_mfma_f32_32x32x16_f16(a2[f].v, Bhh1[f], accB, 0, 0, 0);
        }

        // ---- gate exchange (loop-end barrier covers previous readers) ----
#pragma unroll
        for (int r = 0; r < 16; ++r) {
            int m = mi * 32 + (r & 3) + 8 * (r >> 2) + 4 * nh;
            ex[(ki * 64 + m) * 33 + n] = accA[r];
            ex[((2 + ki) * 64 + m) * 33 + n] = accB[r];
        }
        __syncthreads();

        // ---- cell update: all 4 waves; lane=batch, 4 units each ----
        const bool cact = lyr ? l1 : l0;
        if (cact) {
            const int t = lyr ? tau - 1 : tau;
            const float* e0 = ex + (lyr * 2 + 0) * (64 * 33) + lane * 33;
            const float* e1 = ex + (lyr * 2 + 1) * (64 * 33) + lane * 33;
            f16 hh[4];
            f16x4 xi = __builtin_bit_cast(f16x4, gq0);
            f16x4 xf = __builtin_bit_cast(f16x4, gq1);
            f16x4 xg = __builtin_bit_cast(f16x4, gq2);
            f16x4 xo = __builtin_bit_cast(f16x4, gq3);
            const bool hasx = (lyr == 0) && (idxq >= 0);
#pragma unroll
            for (int uu = 0; uu < 4; ++uu) {
                int nc = q * 4 + uu;
                float gi = e0[nc]      + e1[nc]      + bsh[lyr * 32 + nc];
                float gf = e0[8 + nc]  + e1[8 + nc]  + bsh[lyr * 32 + 8 + nc];
                float gg = e0[16 + nc] + e1[16 + nc] + bsh[lyr * 32 + 16 + nc];
                float go = e0[24 + nc] + e1[24 + nc] + bsh[lyr * 32 + 24 + nc];
                if (hasx) {
                    gi += (float)xi[uu]; gf += (float)xf[uu];
                    gg += (float)xg[uu]; go += (float)xo[uu];
                }
                float c_ = (t > 0) ? cst[uu] : 0.0f;
                float cn = sigmoidf_(gf) * c_ + sigmoidf_(gi) * tanhf_(gg);
                float hv = sigmoidf_(go) * tanhf_(cn);
                cst[uu] = cn;
                hh[uu] = (f16)hv;
            }
            union HP { f16x4 h; u64 d; } p;
            p.h = (f16x4){hh[0], hh[1], hh[2], hh[3]};
            u64* hb = lyr ? (a.h2 + (size_t)t * TWORDS) : (a.h1 + (size_t)t * TWORDS);
            cstore(hb + (size_t)wg * 128 + lane * 2 + q, p.d);
        }

        // ---- x-gather prefetch for tick tau+1 (issued before the barrier,
        //      lands during the poll; gq registers were consumed above) ----
        if (w < 2 && tau + 1 < SEQ) {
            idxq = (sraw >= 0) ? sraw + NSK * ((craw == 1) ? 0 : 1) : -1;
            const uint2* gp = (const uint2*)(a.W0P +
                (size_t)((idxq >= 0) ? idxq : 0) * 2048 + wg * 32 + q * 4);
            gq0 = gp[0]; gq1 = gp[2]; gq2 = gp[4]; gq3 = gp[6];
            if (tau + 2 < SEQ) {
                sraw = a.skills[lane * SEQ + tau + 2];
                craw = a.corrects[lane * SEQ + tau + 2];
            }
        }

        // ---- barrier: syncthreads drains h-stores; all waves poll padded flags ----
        __syncthreads();
        if (tid == 0)
            __hip_atomic_store(&a.arrive[wg * 16], (u32)(tau + 1), __ATOMIC_RELAXED,
                               __HIP_MEMORY_SCOPE_AGENT);
        if (tau < SEQ) {
            const u32 want = (u32)(tau + 1);
            int guard = 0;
            while (true) {
                u32 v = __hip_atomic_load(&a.arrive[lane * 16], __ATOMIC_RELAXED,
                                          __HIP_MEMORY_SCOPE_AGENT);
                if (__ballot(v < want) == 0ull) break;
                __builtin_amdgcn_s_sleep(1);
                if (++guard > (1 << 20)) break;   // visible failure, never hang
            }
            // keep next tick's plain h-loads from hoisting above the poll
            asm volatile("" ::: "memory");
            __builtin_amdgcn_sched_barrier(0);
        }
    }
}

// ---- projection (MFMA): out[b][t][n] = sigmoid(h2[t][b][:] . fcW[n] + fcb[n])
// block = 4 timesteps x 64 cols; wave w = batches [w*16, w*16+16) over those 4 t.
__global__ __launch_bounds__(256) void proj_mfma(
    const u64* __restrict__ h2, const f16* __restrict__ fcwh,
    const float* __restrict__ fcb, float* __restrict__ out)
{
    const int tg = blockIdx.x >> 4;     // t-group (4 timesteps)
    const int nt = blockIdx.x & 15;     // 64-col group
    const int tid = threadIdx.x;
    const int l = tid & 63;
    const int w = tid >> 6;             // batch-tile
    const int col = l & 15;
    const int kb = l >> 4;

    f32x4 acc[4][4];                    // [t-local j][n-tile]
#pragma unroll
    for (int j = 0; j < 4; ++j)
#pragma unroll
        for (int v = 0; v < 4; ++v) acc[j][v] = (f32x4){0, 0, 0, 0};

    float fb[4];
#pragma unroll
    for (int v = 0; v < 4; ++v) fb[v] = fcb[nt * 64 + v * 16 + col];

    union AF { uint4 u; f16x8 v; };

#pragma unroll 2
    for (int f = 0; f < 16; ++f) {
        f16x8 Bf[4];
#pragma unroll
        for (int v = 0; v < 4; ++v) {
            int nn = nt * 64 + v * 16 + col;
            Bf[v] = *(const f16x8*)(fcwh + (size_t)nn * HID + f * 32 + kb * 8);
        }
#pragma unroll
        for (int j = 0; j < 4; ++j) {
            const u64* hp = h2 + (size_t)(tg * 4 + j) * TWORDS
                          + ((f * 4 + kb) * 128 + (w * 16 + col) * 2);
            AF av; av.u = *(const uint4*)hp;
#pragma unroll
            for (int v = 0; v < 4; ++v)
                acc[j][v] = __builtin_amdgcn_mfma_f32_16x16x32_f16(av.v, Bf[v], acc[j][v], 0, 0, 0);
        }
    }

    // epilogue: C layout col=lane&15, row=(lane>>4)*4+r
#pragma unroll
    for (int j = 0; j < 4; ++j) {
        int t = tg * 4 + j;
#pragma unroll
        for (int v = 0; v < 4; ++v) {
            int nn = nt * 64 + v * 16 + col;
#pragma unroll
            for (int r = 0; r < 4; ++r) {
                int b = w * 16 + kb * 4 + r;
                out[((size_t)b * SEQ + t) * NSK + nn] = sigmoidf_(acc[j][v][r] + fb[v]);
            }
        }
    }
}

extern "C" void kernel_launch(void* const* d_in, const int* in_sizes, int n_in,
                              void* d_out, int out_size, void* d_ws, size_t ws_size,
                              hipStream_t stream) {
    (void)in_sizes; (void)n_in; (void)out_size; (void)ws_size;

    const int*   skills   = (const int*)d_in[0];
    const int*   corrects = (const int*)d_in[1];
    const float* Wih0 = (const float*)d_in[2];
    const float* Whh0 = (const float*)d_in[3];
    const float* bih0 = (const float*)d_in[4];
    const float* bhh0 = (const float*)d_in[5];
    const float* Wih1 = (const float*)d_in[6];
    const float* Whh1 = (const float*)d_in[7];
    const float* bih1 = (const float*)d_in[8];
    const float* bhh1 = (const float*)d_in[9];
    const float* fcW  = (const float*)d_in[10];
    const float* fcb  = (const float*)d_in[11];

    char* ws = (char*)d_ws;
    u64*  h1    = (u64*)(ws + H1_OFF);
    u64*  h2    = (u64*)(ws + H2_OFF);
    f16*  whh0h = (f16*)(ws + WHH0_OFF);
    f16*  wih1h = (f16*)(ws + WIH1_OFF);
    f16*  whh1h = (f16*)(ws + WHH1_OFF);
    f16*  fcwh  = (f16*)(ws + FCW_OFF);
    float* b0   = (float*)(ws + B0_OFF);
    float* b1   = (float*)(ws + B1_OFF);
    f16*  w0p   = (f16*)(ws + W0P_OFF);
    u32*  flags = (u32*)(ws + FLG_OFF);

    prep_kernel<<<4096, 256, 0, stream>>>(Whh0, Wih1, Whh1, fcW, bih0, bhh0,
                                          bih1, bhh1, whh0h, wih1h, whh1h, fcwh,
                                          b0, b1, flags);
    w0p_kernel<<<1024, 256, 0, stream>>>(Wih0, w0p);

    PArgs pa;
    pa.skills = skills; pa.corrects = corrects; pa.W0P = w0p;
    pa.Whh0 = whh0h; pa.Wih1 = wih1h; pa.Whh1 = whh1h;
    pa.b0 = b0; pa.b1 = b1; pa.h1 = h1; pa.h2 = h2;
    pa.arrive = flags;

    lstm_mfma<<<NWG, 256, 0, stream>>>(pa);

    proj_mfma<<<2048, 256, 0, stream>>>(h2, fcwh, fcb, (float*)d_out);
}